// Round 21
// baseline (86.193 us; speedup 1.0000x reference)
//
#include <hip/hip_runtime.h>
#include <math.h>

#define LL 4096
#define CC 128
#define SS 64
#define CLEN 32    // steps per chunk (wave)
#define GW 8       // chunks (waves) per group
#define NG 16      // groups; NG*GW*CLEN = LL
#define CS 8192    // CC*SS
#define PPB 4      // groups per fused block
#define NBLK 512   // CC * NG / PPB ; exactly 2 blocks/CU -> all co-resident
#define LOG2E 1.44269504088896f

// ---------------- kernel 1: projections (B, Cm, dtT) + xT (R12 verbatim) ----
// + block 0 resets the grid-barrier counter for the fused kernel.
__global__ __launch_bounds__(256) void k_proj(
    const float* __restrict__ x,
    const float* __restrict__ Bk, const float* __restrict__ Bb,
    const float* __restrict__ Ck, const float* __restrict__ Cb,
    const float* __restrict__ Dk, const float* __restrict__ Db,
    float* __restrict__ Bmat, float* __restrict__ Cmat,
    float* __restrict__ DTmT, float* __restrict__ xT,
    int* __restrict__ bar)
{
    if (blockIdx.x == 0 && threadIdx.x == 0)
        __hip_atomic_store(bar, 0, __ATOMIC_RELAXED, __HIP_MEMORY_SCOPE_AGENT);
    __shared__ float xs[CC][20];
    const int r0 = blockIdx.x * 16;
    const int t = threadIdx.x;
    {
        const int r = t >> 4, k8 = (t & 15) * 8;
        const float4 v0 = *(const float4*)&x[(r0 + r) * CC + k8];
        const float4 v1 = *(const float4*)&x[(r0 + r) * CC + k8 + 4];
        xs[k8+0][r] = v0.x; xs[k8+1][r] = v0.y; xs[k8+2][r] = v0.z; xs[k8+3][r] = v0.w;
        xs[k8+4][r] = v1.x; xs[k8+5][r] = v1.y; xs[k8+6][r] = v1.z; xs[k8+7][r] = v1.w;
    }
    __syncthreads();
    {   // emit x transposed [C][L]
        const int k = t >> 1, half = (t & 1) * 8;
        const float4 a = *(const float4*)&xs[k][half];
        const float4 b = *(const float4*)&xs[k][half + 4];
        *(float4*)&xT[k * LL + r0 + half]     = a;
        *(float4*)&xT[k * LL + r0 + half + 4] = b;
    }
    const int tc = t & 63, tr = t >> 6;
    const float* Wb; int wstride, wo;
    if (tc < 16)      { Wb = Bk; wstride = SS; wo = 4 * tc; }
    else if (tc < 32) { Wb = Ck; wstride = SS; wo = 4 * tc - 64; }
    else              { Wb = Dk; wstride = CC; wo = 4 * tc - 128; }
    float acc[4][4];
#pragma unroll
    for (int r = 0; r < 4; ++r)
#pragma unroll
        for (int j = 0; j < 4; ++j) acc[r][j] = 0.0f;
    for (int k = 0; k < CC; ++k) {
        const float4 wq = *(const float4*)(Wb + k * wstride + wo);
        const float4 xq = *(const float4*)&xs[k][4 * tr];
        const float wv[4] = {wq.x, wq.y, wq.z, wq.w};
        const float xv[4] = {xq.x, xq.y, xq.z, xq.w};
#pragma unroll
        for (int r = 0; r < 4; ++r)
#pragma unroll
            for (int j = 0; j < 4; ++j) acc[r][j] = fmaf(xv[r], wv[j], acc[r][j]);
    }
    const int rb = r0 + 4 * tr;
    if (tc < 32) {
        const float* bb = (tc < 16) ? Bb : Cb;
        const float add = (tc < 16) ? 1.0f : 0.0f;
        float bias[4];
#pragma unroll
        for (int j = 0; j < 4; ++j) bias[j] = add + bb[wo + j];
        float* dst = (tc < 16) ? Bmat : Cmat;
#pragma unroll
        for (int r = 0; r < 4; ++r) {
            const float4 o = make_float4(acc[r][0] + bias[0], acc[r][1] + bias[1],
                                         acc[r][2] + bias[2], acc[r][3] + bias[3]);
            *(float4*)&dst[(rb + r) * SS + wo] = o;
        }
    } else {
#pragma unroll
        for (int j = 0; j < 4; ++j) {
            const float bj = Db[wo + j] + 0.000244140625f;
            float sp[4];
#pragma unroll
            for (int r = 0; r < 4; ++r) {
                const float z = acc[r][j] + bj;
                sp[r] = fmaxf(z, 0.0f) + log1pf(__expf(-fabsf(z)));
            }
            *(float4*)&DTmT[(wo + j) * LL + rb] = make_float4(sp[0], sp[1], sp[2], sp[3]);
        }
    }
}

// ------- fused: chunk aggregates + grid barrier + prefix + rewalk/emit -------
// 512 blocks x 512 thr; block = (c, quadrant q of PPB=4 groups); 2 blocks/CU.
__global__ __launch_bounds__(512, 4) void k_fused(
    const float* __restrict__ xT, const float* __restrict__ A_log,
    const float* __restrict__ Bmat, const float* __restrict__ Cmat,
    const float* __restrict__ DTmT,
    float2* __restrict__ GaGu, int* __restrict__ bar,
    float* __restrict__ y)
{
    __shared__ float2 agg[PPB][GW][SS];   // 16 KB, retained phase1 -> phase3
    __shared__ float hgs[PPB][SS];        // 1 KB
    const int t = threadIdx.x;
    const int lane = t & 63;
    const int w = __builtin_amdgcn_readfirstlane(t >> 6);
    const int c  = blockIdx.x >> 2;       // SGPR
    const int g0 = (blockIdx.x & 3) * PPB;// SGPR
    const int j  = c * SS + lane;
    const float A = -__expf(A_log[j]);
    const float A2 = A * LOG2E;           // At = 2^(A2*dt)
    const float invA = 1.0f / A;
    const float* dtc = DTmT + c * LL;
    const float* xc  = xT   + c * LL;

    // ---- phase 1: chunk aggregates for PPB groups ----
    for (int pi = 0; pi < PPB; ++pi) {
        const int l0 = ((g0 + pi) * GW + w) * CLEN;
        const float* dtp = dtc + l0;
        const float* xp  = xc + l0;
        const float* Bp  = Bmat + l0 * SS + lane;
        float ap = 1.0f, uc = 0.0f;
#pragma unroll
        for (int i = 0; i < CLEN; ++i) {
            const float At = __builtin_amdgcn_exp2f(A2 * dtp[i]);
            const float u  = (At - 1.0f) * invA * (Bp[i * SS] * xp[i]);
            ap *= At;
            uc = fmaf(At, uc, u);
        }
        agg[pi][w][lane] = make_float2(ap, uc);
    }
    __syncthreads();
    if (w < PPB) {   // wave w composes group g0+w (time order)
        float ga = 1.0f, gu = 0.0f;
#pragma unroll
        for (int k = 0; k < GW; ++k) {
            const float2 tt = agg[w][k][lane];
            gu = fmaf(tt.x, gu, tt.y);
            ga *= tt.x;
        }
        GaGu[(g0 + w) * CS + j] = make_float2(ga, gu);
    }
    __syncthreads();

    // ---- grid barrier (all NBLK blocks co-resident by construction) ----
    if (t == 0) {
        __builtin_amdgcn_fence(__ATOMIC_RELEASE, "agent");
        __hip_atomic_fetch_add(bar, 1, __ATOMIC_RELAXED, __HIP_MEMORY_SCOPE_AGENT);
        while (__hip_atomic_load(bar, __ATOMIC_RELAXED, __HIP_MEMORY_SCOPE_AGENT) < NBLK)
            __builtin_amdgcn_s_sleep(2);
        __builtin_amdgcn_fence(__ATOMIC_ACQUIRE, "agent");
    }
    __syncthreads();

    // ---- phase 2: cross-group prefixes for this block's PPB groups (wave 0) --
    if (w == 0) {
        float2 ggr[NG - 1];
#pragma unroll
        for (int gg = 0; gg < NG - 1; ++gg) ggr[gg] = GaGu[gg * CS + j];
        float hg = 0.0f;
#pragma unroll
        for (int gg = 0; gg < NG; ++gg) {
            if (gg >= g0 && gg < g0 + PPB) hgs[gg - g0][lane] = hg;
            if (gg < NG - 1) hg = fmaf(ggr[gg].x, hg, ggr[gg].y);
        }
    }
    __syncthreads();

    // ---- phase 3: per group: in-block prefix + rewalk + butterfly emit ----
    for (int pi = 0; pi < PPB; ++pi) {
        const int g = g0 + pi;
        const int l0 = (g * GW + w) * CLEN;
        const float* dtp = dtc + l0;
        const float* xp  = xc + l0;
        const float* Bp  = Bmat + l0 * SS + lane;
        const float* Cp  = Cmat + l0 * SS + lane;
        // exclusive prefix over chunks 0..w-1 of this group (trip wave-uniform)
        float ea = 1.0f, eu = 0.0f;
        for (int k = 0; k < w; ++k) {
            const float2 tt = agg[pi][k][lane];
            eu = fmaf(tt.x, eu, tt.y);
            ea *= tt.x;
        }
        float h = fmaf(ea, hgs[pi][lane], eu);
        float at[CLEN], uu[CLEN];
#pragma unroll
        for (int i = 0; i < CLEN; ++i) {
            at[i] = __builtin_amdgcn_exp2f(A2 * dtp[i]);
            uu[i] = (at[i] - 1.0f) * invA * (Bp[i * SS] * xp[i]);
        }
#pragma unroll
        for (int i = 0; i < CLEN; ++i) {
            h = fmaf(at[i], h, uu[i]);
            uu[i] = Cp[i * SS] * h;
        }
        // 32-row x 64-lane register-halving transpose-reduce
#pragma unroll
        for (int k = 0; k < 5; ++k) {
            const int d = 1 << k;
            const bool hi = (lane & d) != 0;
#pragma unroll
            for (int i2 = 0; i2 < (CLEN >> (k + 1)); ++i2) {
                const float a = uu[2 * i2], b = uu[2 * i2 + 1];
                const float send = hi ? a : b;
                const float tt = __shfl_xor(send, d, 64);
                uu[i2] = (hi ? b : a) + tt;
            }
        }
        const float tt = __shfl_xor(uu[0], 32, 64);
        const float yv = uu[0] + tt;
        if (lane < 32) y[(l0 + lane) * CC + c] = yv;
    }
}

extern "C" void kernel_launch(void* const* d_in, const int* in_sizes, int n_in,
                              void* d_out, int out_size, void* d_ws, size_t ws_size,
                              hipStream_t stream)
{
    const float* x  = (const float*)d_in[0];
    const float* Al = (const float*)d_in[1];
    const float* Bk = (const float*)d_in[2];
    const float* Bb = (const float*)d_in[3];
    const float* Ck = (const float*)d_in[4];
    const float* Cb = (const float*)d_in[5];
    const float* Dk = (const float*)d_in[6];
    const float* Db = (const float*)d_in[7];
    float* y  = (float*)d_out;
    float* ws = (float*)d_ws;

    float*  Bmat = ws;                        // [L][S]   1 MB
    float*  Cmat = Bmat + LL * SS;            // [L][S]   1 MB
    float*  DTmT = Cmat + LL * SS;            // [C][L]   2 MB
    float*  xT   = DTmT + CC * LL;            // [C][L]   2 MB
    float2* GaGu = (float2*)(xT + CC * LL);   // [NG][CS] 1 MB
    int*    bar  = (int*)(GaGu + NG * CS);    // 4 B grid-barrier counter

    k_proj <<<LL / 16, 256, 0, stream>>>(x, Bk, Bb, Ck, Cb, Dk, Db, Bmat, Cmat, DTmT, xT, bar);
    k_fused<<<NBLK,    512, 0, stream>>>(xT, Al, Bmat, Cmat, DTmT, GaGu, bar, y);
}

// Round 22
// 46.898 us; speedup vs baseline: 1.8379x; 1.8379x over previous
//
#include <hip/hip_runtime.h>
#include <math.h>

#define LL 4096
#define CC 128
#define SS 64
#define CLEN 32    // steps per chunk (wave)
#define GW 8       // chunks (waves) per group/block
#define NG 16      // groups; NG*GW*CLEN = LL
#define CS 8192    // CC*SS
#define LOG2E 1.44269504088896f

// ---------------- kernel 1: projections (B, Cm, dtT) + xT ----------------
__global__ __launch_bounds__(256) void k_proj(
    const float* __restrict__ x,
    const float* __restrict__ Bk, const float* __restrict__ Bb,
    const float* __restrict__ Ck, const float* __restrict__ Cb,
    const float* __restrict__ Dk, const float* __restrict__ Db,
    float* __restrict__ Bmat, float* __restrict__ Cmat,
    float* __restrict__ DTmT, float* __restrict__ xT)
{
    __shared__ float xs[CC][20];
    const int r0 = blockIdx.x * 16;
    const int t = threadIdx.x;
    {
        const int r = t >> 4, k8 = (t & 15) * 8;
        const float4 v0 = *(const float4*)&x[(r0 + r) * CC + k8];
        const float4 v1 = *(const float4*)&x[(r0 + r) * CC + k8 + 4];
        xs[k8+0][r] = v0.x; xs[k8+1][r] = v0.y; xs[k8+2][r] = v0.z; xs[k8+3][r] = v0.w;
        xs[k8+4][r] = v1.x; xs[k8+5][r] = v1.y; xs[k8+6][r] = v1.z; xs[k8+7][r] = v1.w;
    }
    __syncthreads();
    {   // emit x transposed [C][L]
        const int k = t >> 1, half = (t & 1) * 8;
        const float4 a = *(const float4*)&xs[k][half];
        const float4 b = *(const float4*)&xs[k][half + 4];
        *(float4*)&xT[k * LL + r0 + half]     = a;
        *(float4*)&xT[k * LL + r0 + half + 4] = b;
    }
    const int tc = t & 63, tr = t >> 6;
    const float* Wb; int wstride, wo;
    if (tc < 16)      { Wb = Bk; wstride = SS; wo = 4 * tc; }
    else if (tc < 32) { Wb = Ck; wstride = SS; wo = 4 * tc - 64; }
    else              { Wb = Dk; wstride = CC; wo = 4 * tc - 128; }
    float acc[4][4];
#pragma unroll
    for (int r = 0; r < 4; ++r)
#pragma unroll
        for (int j = 0; j < 4; ++j) acc[r][j] = 0.0f;
    for (int k = 0; k < CC; ++k) {
        const float4 wq = *(const float4*)(Wb + k * wstride + wo);
        const float4 xq = *(const float4*)&xs[k][4 * tr];
        const float wv[4] = {wq.x, wq.y, wq.z, wq.w};
        const float xv[4] = {xq.x, xq.y, xq.z, xq.w};
#pragma unroll
        for (int r = 0; r < 4; ++r)
#pragma unroll
            for (int j = 0; j < 4; ++j) acc[r][j] = fmaf(xv[r], wv[j], acc[r][j]);
    }
    const int rb = r0 + 4 * tr;
    if (tc < 32) {
        const float* bb = (tc < 16) ? Bb : Cb;
        const float add = (tc < 16) ? 1.0f : 0.0f;
        float bias[4];
#pragma unroll
        for (int j = 0; j < 4; ++j) bias[j] = add + bb[wo + j];
        float* dst = (tc < 16) ? Bmat : Cmat;
#pragma unroll
        for (int r = 0; r < 4; ++r) {
            const float4 o = make_float4(acc[r][0] + bias[0], acc[r][1] + bias[1],
                                         acc[r][2] + bias[2], acc[r][3] + bias[3]);
            *(float4*)&dst[(rb + r) * SS + wo] = o;
        }
    } else {
#pragma unroll
        for (int j = 0; j < 4; ++j) {
            const float bj = Db[wo + j] + 0.000244140625f;
            float sp[4];
#pragma unroll
            for (int r = 0; r < 4; ++r) {
                const float z = acc[r][j] + bj;
                sp[r] = fmaxf(z, 0.0f) + log1pf(__expf(-fabsf(z)));
            }
            *(float4*)&DTmT[(wo + j) * LL + rb] = make_float4(sp[0], sp[1], sp[2], sp[3]);
        }
    }
}

// ------- kernel 2: group aggregates -------
__global__ __launch_bounds__(512, 4) void k_sweep1(
    const float* __restrict__ xT, const float* __restrict__ A_log,
    const float* __restrict__ Bmat, const float* __restrict__ DTmT,
    float2* __restrict__ GaGu)
{
    __shared__ float2 agg[GW][SS];
    const int lane = threadIdx.x & 63;
    const int w = __builtin_amdgcn_readfirstlane(threadIdx.x >> 6);
    const int c = blockIdx.x >> 4;          // SGPR
    const int g = blockIdx.x & (NG - 1);    // SGPR
    const int j = c * SS + lane;
    const float A = -__expf(A_log[j]);
    const float A2 = A * LOG2E;             // At = 2^(A2*dt)
    const float invA = 1.0f / A;
    const int l0 = (g * GW + w) * CLEN;
    const float* dtp = DTmT + c * LL + l0;
    const float* xp  = xT   + c * LL + l0;
    const float* Bp  = Bmat + l0 * SS + lane;
    float ap = 1.0f, uc = 0.0f;
#pragma unroll
    for (int i = 0; i < CLEN; ++i) {
        const float At = __builtin_amdgcn_exp2f(A2 * dtp[i]);
        const float u  = (At - 1.0f) * invA * (Bp[i * SS] * xp[i]);
        ap *= At;
        uc = fmaf(At, uc, u);
    }
    agg[w][lane] = make_float2(ap, uc);
    __syncthreads();
    if (w == 0) {
        float ga = 1.0f, gu = 0.0f;
#pragma unroll
        for (int k = 0; k < GW; ++k) {
            const float2 t = agg[k][lane];
            gu = fmaf(t.x, gu, t.y);
            ga *= t.x;
        }
        GaGu[g * CS + j] = make_float2(ga, gu);
    }
}

// ------- kernel 3: wave0-prologue + reg-cached rewalk + emit -------
__global__ __launch_bounds__(512) void k_emit(
    const float* __restrict__ xT, const float* __restrict__ A_log,
    const float* __restrict__ Bmat, const float* __restrict__ Cmat,
    const float* __restrict__ DTmT,
    const float2* __restrict__ GaGu,
    float* __restrict__ y)
{
    __shared__ float2 agg[GW][SS];
    __shared__ float hgs[SS];
    const int lane = threadIdx.x & 63;
    const int w = __builtin_amdgcn_readfirstlane(threadIdx.x >> 6);
    const int c = blockIdx.x >> 4;          // SGPR
    const int g = blockIdx.x & (NG - 1);    // SGPR
    const int j = c * SS + lane;
    const float A = -__expf(A_log[j]);
    const float A2 = A * LOG2E;
    const float invA = 1.0f / A;
    if (w == 0) {
        float hg = 0.0f;
        float2 ggr[NG - 1];
#pragma unroll
        for (int gg = 0; gg < NG - 1; ++gg) ggr[gg] = GaGu[gg * CS + j];
#pragma unroll
        for (int gg = 0; gg < NG - 1; ++gg)
            hg = (gg < g) ? fmaf(ggr[gg].x, hg, ggr[gg].y) : hg;
        hgs[lane] = hg;
    }
    const int l0 = (g * GW + w) * CLEN;
    const float* dtp = DTmT + c * LL + l0;
    const float* xp  = xT   + c * LL + l0;
    const float* Bp  = Bmat + l0 * SS + lane;
    const float* Cp  = Cmat + l0 * SS + lane;
    float at[CLEN], uu[CLEN];
    {
        float ap = 1.0f, uc = 0.0f;
#pragma unroll
        for (int i = 0; i < CLEN; ++i) {
            at[i] = __builtin_amdgcn_exp2f(A2 * dtp[i]);
            uu[i] = (at[i] - 1.0f) * invA * (Bp[i * SS] * xp[i]);
            ap *= at[i];
            uc = fmaf(at[i], uc, uu[i]);
        }
        agg[w][lane] = make_float2(ap, uc);
    }
    __syncthreads();
    const float hg = hgs[lane];
    float ea = 1.0f, eu = 0.0f;
    for (int k = 0; k < w; ++k) {
        const float2 t = agg[k][lane];
        eu = fmaf(t.x, eu, t.y);
        ea *= t.x;
    }
    float h = fmaf(ea, hg, eu);
#pragma unroll
    for (int i = 0; i < CLEN; ++i) {
        h = fmaf(at[i], h, uu[i]);
        uu[i] = Cp[i * SS] * h;
    }
#pragma unroll
    for (int k = 0; k < 5; ++k) {
        const int d = 1 << k;
        const bool hi = (lane & d) != 0;
#pragma unroll
        for (int i2 = 0; i2 < (CLEN >> (k + 1)); ++i2) {
            const float a = uu[2 * i2], b = uu[2 * i2 + 1];
            const float send = hi ? a : b;
            const float t = __shfl_xor(send, d, 64);
            uu[i2] = (hi ? b : a) + t;
        }
    }
    const float t = __shfl_xor(uu[0], 32, 64);
    const float yv = uu[0] + t;
    if (lane < 32) y[(l0 + lane) * CC + c] = yv;
}

extern "C" void kernel_launch(void* const* d_in, const int* in_sizes, int n_in,
                              void* d_out, int out_size, void* d_ws, size_t ws_size,
                              hipStream_t stream)
{
    const float* x  = (const float*)d_in[0];
    const float* Al = (const float*)d_in[1];
    const float* Bk = (const float*)d_in[2];
    const float* Bb = (const float*)d_in[3];
    const float* Ck = (const float*)d_in[4];
    const float* Cb = (const float*)d_in[5];
    const float* Dk = (const float*)d_in[6];
    const float* Db = (const float*)d_in[7];
    float* y  = (float*)d_out;
    float* ws = (float*)d_ws;

    float*  Bmat = ws;                        // [L][S]   1 MB
    float*  Cmat = Bmat + LL * SS;            // [L][S]   1 MB
    float*  DTmT = Cmat + LL * SS;            // [C][L]   2 MB
    float*  xT   = DTmT + CC * LL;            // [C][L]   2 MB
    float2* GaGu = (float2*)(xT + CC * LL);   // [NG][CS] 1 MB

    k_proj  <<<LL / 16, 256, 0, stream>>>(x, Bk, Bb, Ck, Cb, Dk, Db, Bmat, Cmat, DTmT, xT);
    k_sweep1<<<CC * NG, 512, 0, stream>>>(xT, Al, Bmat, DTmT, GaGu);
    k_emit  <<<CC * NG, 512, 0, stream>>>(xT, Al, Bmat, Cmat, DTmT, GaGu, y);
}